// Round 7
// baseline (234.777 us; speedup 1.0000x reference)
//
#include <hip/hip_runtime.h>
#include <hip/hip_bf16.h>
#include <math.h>

#define NNODES 50000
#define FIN 256
#define HH 4
#define CC 32
#define D1 128   // H*C
#define CLS 16
#define NB ((NNODES + 1023) / 1024)   // 49 scan blocks

typedef __attribute__((ext_vector_type(8))) short bfrag8;   // 8 bf16 = 4 VGPRs
typedef __attribute__((ext_vector_type(4))) float facc4;

__device__ __forceinline__ float lrelu(float x){ return x > 0.f ? x : 0.2f*x; }

__device__ __forceinline__ unsigned short f2bu(float x){
  __hip_bfloat16 h = __float2bfloat16(x);
  return *reinterpret_cast<unsigned short*>(&h);
}
__device__ __forceinline__ unsigned int pbf(float a, float b){
  return (unsigned int)f2bu(a) | ((unsigned int)f2bu(b) << 16);
}
__device__ __forceinline__ float2 bf2x(unsigned int u){
  float2 r;
  r.x = __uint_as_float(u << 16);
  r.y = __uint_as_float(u & 0xffff0000u);
  return r;
}

// ---------------- W1 prep: Wt[c][k] = bf16(W1[k][c]) ----------------
__global__ void wprep_kernel(const float* __restrict__ W, unsigned short* __restrict__ Wt) {
  int t = blockIdx.x*256 + threadIdx.x;
  if (t >= FIN*D1) return;
  int k = t >> 7, c = t & 127;
  Wt[c*FIN + k] = f2bu(W[t]);
}

// ---------------- GEMM1 via MFMA: h1b = bf16pairs(x @ W1) ----------------
// block: 64 rows x 128 cols x K=256. 4 waves; wave w owns rows w*16..w*16+15.
// h1b[i][p] packs channels (p, p+64) — p = ct*16+ocol, +64 = ct+4.
__global__ __launch_bounds__(256) void gemm1_mfma(const float* __restrict__ x,
                                                  const unsigned int* __restrict__ Wt,
                                                  unsigned int* __restrict__ h1b) {
  __shared__ unsigned int Bs[128*256/2];    // 64 KB: Wt swizzled
  __shared__ unsigned int As[64*64/2];      // 8 KB: x tile (64 rows x 64 k) swizzled
  int tid = threadIdx.x;
  int wv = tid >> 6, lane = tid & 63;
  int r0 = blockIdx.x * 64;

  // stage all of Wt -> Bs (16B chunk w16 = c*32 + k8), XOR-swizzle byte^=(c&7)<<4
  for (int it = 0; it < 16; it++) {
    int w16 = it*256 + tid;
    int c = w16 >> 5, k8 = w16 & 31;
    uint4 v = ((const uint4*)Wt)[w16];
    int byt = (c*512 + k8*16) ^ ((c&7)<<4);
    *(uint4*)((char*)Bs + byt) = v;
  }

  facc4 acc[8];
  #pragma unroll
  for (int t=0;t<8;t++) acc[t] = (facc4){0.f,0.f,0.f,0.f};

  int arow = tid >> 2, apart = tid & 3;     // A staging: row, 64B source chunk
  int mrow = lane & 15, kb = lane >> 4;     // MFMA fragment indices

  for (int stage = 0; stage < 4; stage++) {
    int gr = r0 + arow;
    const float* src = x + (size_t)gr*FIN + stage*64 + apart*16;
    float4 f0, f1, f2, f3;
    if (gr < NNODES) {
      f0 = *(const float4*)(src);
      f1 = *(const float4*)(src+4);
      f2 = *(const float4*)(src+8);
      f3 = *(const float4*)(src+12);
    } else {
      f0 = f1 = f2 = f3 = make_float4(0.f,0.f,0.f,0.f);
    }
    uint4 u0, u1;
    u0.x = pbf(f0.x,f0.y); u0.y = pbf(f0.z,f0.w);
    u0.z = pbf(f1.x,f1.y); u0.w = pbf(f1.z,f1.w);
    u1.x = pbf(f2.x,f2.y); u1.y = pbf(f2.z,f2.w);
    u1.z = pbf(f3.x,f3.y); u1.w = pbf(f3.z,f3.w);
    __syncthreads();
    int b0 = (arow*128 + apart*32) ^ ((arow&7)<<4);
    int b1 = (arow*128 + apart*32 + 16) ^ ((arow&7)<<4);
    *(uint4*)((char*)As + b0) = u0;
    *(uint4*)((char*)As + b1) = u1;
    __syncthreads();
    #pragma unroll
    for (int ks = 0; ks < 2; ks++) {
      int row = wv*16 + mrow;
      int abyt = (row*128 + ks*64 + kb*16) ^ ((row&7)<<4);
      bfrag8 afrag = *(bfrag8*)((char*)As + abyt);
      #pragma unroll
      for (int ct = 0; ct < 8; ct++) {
        int c = ct*16 + mrow;
        int bbyt = (c*512 + stage*128 + ks*64 + kb*16) ^ ((c&7)<<4);
        bfrag8 bfrag = *(bfrag8*)((char*)Bs + bbyt);
        acc[ct] = __builtin_amdgcn_mfma_f32_16x16x32_bf16(afrag, bfrag, acc[ct], 0, 0, 0);
      }
    }
  }
  // epilogue: D layout col=lane&15, row=(lane>>4)*4+reg. Pack (c, c+64) pairs.
  int orow0 = r0 + wv*16 + (lane>>4)*4;
  int ocol = lane & 15;
  #pragma unroll
  for (int r=0; r<4; r++) {
    int gr = orow0 + r;
    if (gr < NNODES) {
      #pragma unroll
      for (int ct=0; ct<4; ct++)
        h1b[(size_t)gr*64 + ct*16 + ocol] = pbf(acc[ct][r], acc[ct+4][r]);
    }
  }
}

// ---------------- per-node alpha for layer 1 (reads bf16 h1b) ----------------
__global__ void alpha1_kernel(const unsigned int* __restrict__ h1b,
                              const float* __restrict__ asrc,
                              const float* __restrict__ adst,
                              float* __restrict__ as1, float* __restrict__ ad1) {
  int t = blockIdx.x * blockDim.x + threadIdx.x;  // i*H + h
  if (t >= NNODES*HH) return;
  int i = t >> 2, h = t & 3;
  const unsigned int* base = h1b + (size_t)i*64 + (h&1)*32;  // pairs p = (h&1)*32 + q
  const float* ap = asrc + h*CC;
  const float* bp = adst + h*CC;
  bool hi = (h >= 2);
  float s=0.f, d=0.f;
  #pragma unroll
  for (int q8=0; q8<8; q8++){
    uint4 u = *(const uint4*)(base + q8*4);
    float v0 = hi ? bf2x(u.x).y : bf2x(u.x).x;
    float v1 = hi ? bf2x(u.y).y : bf2x(u.y).x;
    float v2 = hi ? bf2x(u.z).y : bf2x(u.z).x;
    float v3 = hi ? bf2x(u.w).y : bf2x(u.w).x;
    int q = q8*4;
    s = fmaf(v0, ap[q+0], s); d = fmaf(v0, bp[q+0], d);
    s = fmaf(v1, ap[q+1], s); d = fmaf(v1, bp[q+1], d);
    s = fmaf(v2, ap[q+2], s); d = fmaf(v2, bp[q+2], d);
    s = fmaf(v3, ap[q+3], s); d = fmaf(v3, bp[q+3], d);
  }
  as1[t] = s; ad1[t] = d;
}

// ---------------- CSR build (by dst) ----------------
__global__ void count_kernel(const int* __restrict__ dsts, int* deg, int E) {
  int e = blockIdx.x*blockDim.x + threadIdx.x;
  if (e < E) atomicAdd(&deg[dsts[e]], 1);
}

__global__ __launch_bounds__(1024) void blocksum_kernel(const int* __restrict__ deg,
                                                        int* __restrict__ bsum) {
  int i = blockIdx.x*1024 + threadIdx.x;
  int v = (i < NNODES) ? deg[i] : 0;
  #pragma unroll
  for (int off=1; off<64; off<<=1) v += __shfl_xor(v, off, 64);
  __shared__ int wsum[16];
  int wv = threadIdx.x >> 6, ln = threadIdx.x & 63;
  if (ln == 0) wsum[wv] = v;
  __syncthreads();
  if (threadIdx.x == 0) {
    int s = 0;
    #pragma unroll
    for (int k=0;k<16;k++) s += wsum[k];
    bsum[blockIdx.x] = s;
  }
}

__global__ void scanbase_kernel(const int* __restrict__ bsum, int* __restrict__ bbase) {
  int l = threadIdx.x;                  // one wave of 64, NB<=64
  int orig = (l < NB) ? bsum[l] : 0;
  int v = orig;
  #pragma unroll
  for (int off=1; off<64; off<<=1) { int t = __shfl_up(v, off, 64); if (l >= off) v += t; }
  if (l < NB) bbase[l] = v - orig;      // exclusive
}

__global__ __launch_bounds__(1024) void scanoffs_kernel(const int* __restrict__ deg,
                                                        const int* __restrict__ bbase,
                                                        int* __restrict__ offs,
                                                        int* __restrict__ cursor) {
  int i = blockIdx.x*1024 + threadIdx.x;
  int orig = (i < NNODES) ? deg[i] : 0;
  int v = orig;
  int ln = threadIdx.x & 63, wv = threadIdx.x >> 6;
  #pragma unroll
  for (int off=1; off<64; off<<=1) { int t = __shfl_up(v, off, 64); if (ln >= off) v += t; }
  __shared__ int wsum[16], wbase[16];
  if (ln == 63) wsum[wv] = v;
  __syncthreads();
  if (threadIdx.x == 0) {
    int s = 0;
    #pragma unroll
    for (int k=0;k<16;k++) { wbase[k] = s; s += wsum[k]; }
  }
  __syncthreads();
  int incl = bbase[blockIdx.x] + wbase[wv] + v;
  if (i < NNODES) { offs[i+1] = incl; cursor[i] = incl - orig; }
  if (i == 0) offs[0] = 0;
}

__global__ void place_kernel(const int* __restrict__ srcs, const int* __restrict__ dsts,
                             int* cursor, int* __restrict__ srcsort, int E) {
  int e = blockIdx.x*blockDim.x + threadIdx.x;
  if (e < E) {
    int d = dsts[e];
    int s = srcs[e];
    int p = atomicAdd(&cursor[d], 1);
    // NT store: don't take exclusive L2 ownership of the line on this XCD —
    // random 4B scatters otherwise ping-pong lines across XCD L2s (52 MB
    // writeback for a 3.2 MB payload, measured round 6).
    __builtin_nontemporal_store(s, &srcsort[p]);
  }
}

// ---------------- layer-1 softmax + aggregation (+bias+ELU), no-max softmax ----------------
// lane owns channels {lane, lane+64}; heads hlo=lane>>5, hhi=hlo+2.
__global__ __launch_bounds__(256) void agg1_kernel(
    const unsigned int* __restrict__ h1b, const float* __restrict__ as1,
    const float* __restrict__ ad1, const int* __restrict__ offs,
    const int* __restrict__ srcsort, const float* __restrict__ b1,
    float* __restrict__ out1) {
  __shared__ float exs[4][4][64];   // [warp][head][chunk-slot]
  __shared__ int   ss [4][64];
  int warp = threadIdx.x >> 6;
  int lane = threadIdx.x & 63;
  int i = blockIdx.x * 4 + warp;
  if (i >= NNODES) return;
  int start = offs[i], end = offs[i+1];
  float4 adv = *(const float4*)(ad1 + (size_t)i*4);
  float4 asv = *(const float4*)(as1 + (size_t)i*4);
  float ad[4] = {adv.x, adv.y, adv.z, adv.w};
  float wself[4];
  {
    float av[4] = {asv.x, asv.y, asv.z, asv.w};
    #pragma unroll
    for (int h=0;h<4;h++) wself[h] = expf(lrelu(av[h] + ad[h]));
  }
  int hlo = lane >> 5, hhi = hlo + 2;
  float den[4] = {0.f, 0.f, 0.f, 0.f};
  float accA, accB;
  {
    float2 hv = bf2x(h1b[(size_t)i*64 + lane]);
    accA = wself[hlo] * hv.x; accB = wself[hhi] * hv.y;
  }
  for (int c0 = start; c0 < end; c0 += 64) {
    int cnt = min(64, end - c0);
    int j = c0 + lane;
    if (j < end) {
      int s = srcsort[j];
      float4 a = *(const float4*)(as1 + (size_t)s*4);
      float e0 = expf(lrelu(a.x + ad[0]));
      float e1 = expf(lrelu(a.y + ad[1]));
      float e2 = expf(lrelu(a.z + ad[2]));
      float e3 = expf(lrelu(a.w + ad[3]));
      den[0] += e0; den[1] += e1; den[2] += e2; den[3] += e3;
      exs[warp][0][lane] = e0; exs[warp][1][lane] = e1;
      exs[warp][2][lane] = e2; exs[warp][3][lane] = e3;
      ss[warp][lane] = s;
    }
    #pragma unroll 2
    for (int j2 = 0; j2 < cnt; j2++) {
      int s = ss[warp][j2];
      float2 hv = bf2x(h1b[(size_t)s*64 + lane]);
      accA = fmaf(exs[warp][hlo][j2], hv.x, accA);
      accB = fmaf(exs[warp][hhi][j2], hv.y, accB);
    }
  }
  #pragma unroll
  for (int off=1; off<64; off<<=1) {
    #pragma unroll
    for (int h=0;h<4;h++) den[h] += __shfl_xor(den[h], off, 64);
  }
  float invlo = 1.f / (den[hlo] + wself[hlo] + 1e-16f);
  float invhi = 1.f / (den[hhi] + wself[hhi] + 1e-16f);
  float v0 = accA * invlo + b1[lane];
  float v1 = accB * invhi + b1[lane + 64];
  out1[(size_t)i*D1 + lane]      = v0 > 0.f ? v0 : expm1f(v0);
  out1[(size_t)i*D1 + 64 + lane] = v1 > 0.f ? v1 : expm1f(v1);
}

// ---------------- layer-2 projection + alphas (h2 stored bf16) ----------------
__global__ __launch_bounds__(256) void layer2_proj_kernel(
    const float* __restrict__ out1, const float* __restrict__ W2,
    const float* __restrict__ asrc2, const float* __restrict__ adst2,
    __hip_bfloat16* __restrict__ h2b, float* __restrict__ as2, float* __restrict__ ad2) {
  __shared__ float w_s[D1*CLS];
  for (int l = threadIdx.x; l < D1*CLS; l += 256) w_s[l] = W2[l];
  __syncthreads();
  int warp = threadIdx.x >> 6, lane = threadIdx.x & 63;
  int i = blockIdx.x*4 + warp;
  if (i >= NNODES) return;
  int c = lane & 15, kq = lane >> 4;
  float acc = 0.f;
  const float* xp = out1 + (size_t)i*D1 + kq*32;
  #pragma unroll
  for (int q=0; q<8; q++) {
    float4 v = *(const float4*)(xp + q*4);
    int k = kq*32 + q*4;
    acc = fmaf(v.x, w_s[(k+0)*CLS + c], acc);
    acc = fmaf(v.y, w_s[(k+1)*CLS + c], acc);
    acc = fmaf(v.z, w_s[(k+2)*CLS + c], acc);
    acc = fmaf(v.w, w_s[(k+3)*CLS + c], acc);
  }
  acc += __shfl_xor(acc, 16, 64);
  acc += __shfl_xor(acc, 32, 64);
  if (lane < 16) h2b[(size_t)i*CLS + c] = __float2bfloat16(acc);
  float s = acc * asrc2[c];
  float d = acc * adst2[c];
  #pragma unroll
  for (int off=1; off<16; off<<=1) { s += __shfl_xor(s, off, 64); d += __shfl_xor(d, off, 64); }
  if (lane == 0) { as2[i] = s; ad2[i] = d; }
}

// ---------------- layer-2 softmax + aggregation, single pass ----------------
__global__ __launch_bounds__(256) void agg2_kernel(
    const unsigned int* __restrict__ h2b, const float* __restrict__ as2,
    const float* __restrict__ ad2, const int* __restrict__ offs,
    const int* __restrict__ srcsort, const float* __restrict__ b2,
    float* __restrict__ out) {
  int warp = threadIdx.x >> 6, lane = threadIdx.x & 63;
  int i = blockIdx.x*4 + warp;
  if (i >= NNODES) return;
  int start = offs[i], end = offs[i+1];
  float ad = ad2[i];
  float wself = expf(lrelu(as2[i] + ad));
  int g = lane >> 3, cp = lane & 7;
  float2 acc = make_float2(0.f, 0.f);
  float denp = 0.f;
  if (g == 0) {
    float2 hv = bf2x(h2b[(size_t)i*(CLS/2) + cp]);
    acc.x = wself*hv.x; acc.y = wself*hv.y;
    denp = wself;
  }
  for (int j = start + g; j < end; j += 8) {
    int s = srcsort[j];
    float w = expf(lrelu(as2[s] + ad));
    denp += w;
    float2 hv = bf2x(h2b[(size_t)s*(CLS/2) + cp]);
    acc.x = fmaf(w, hv.x, acc.x);
    acc.y = fmaf(w, hv.y, acc.y);
  }
  #pragma unroll
  for (int off=8; off<64; off<<=1) {
    acc.x += __shfl_xor(acc.x, off, 64);
    acc.y += __shfl_xor(acc.y, off, 64);
    denp  += __shfl_xor(denp,  off, 64);
  }
  if (lane < 8) {
    float inv = 1.f / (denp + 1e-16f);
    float2 o;
    o.x = acc.x * inv + b2[2*cp];
    o.y = acc.y * inv + b2[2*cp+1];
    *(float2*)(out + (size_t)i*CLS + 2*cp) = o;
  }
}

extern "C" void kernel_launch(void* const* d_in, const int* in_sizes, int n_in,
                              void* d_out, int out_size, void* d_ws, size_t ws_size,
                              hipStream_t stream) {
  const float* x     = (const float*)d_in[0];
  const int*   eidx  = (const int*)d_in[1];
  const float* W1    = (const float*)d_in[2];
  const float* asrc1 = (const float*)d_in[3];
  const float* adst1 = (const float*)d_in[4];
  const float* b1    = (const float*)d_in[5];
  const float* W2    = (const float*)d_in[6];
  const float* asrc2 = (const float*)d_in[7];
  const float* adst2 = (const float*)d_in[8];
  const float* b2    = (const float*)d_in[9];
  float* out = (float*)d_out;

  const int E = in_sizes[1] / 2;
  const int* srcs = eidx;
  const int* dsts = eidx + E;

  char* ws = (char*)d_ws;
  size_t off = 0;
  auto alloc = [&](size_t bytes) -> void* {
    void* p = ws + off;
    off = (off + bytes + 255) & ~(size_t)255;
    return p;
  };
  unsigned int*   h1b     = (unsigned int*)alloc((size_t)NNODES*(D1/2)*4);
  float*          out1    = (float*)alloc((size_t)NNODES*D1*4);
  unsigned short* Wt      = (unsigned short*)alloc((size_t)FIN*D1*2);
  float*          as1     = (float*)alloc((size_t)NNODES*HH*4);
  float*          ad1     = (float*)alloc((size_t)NNODES*HH*4);
  __hip_bfloat16* h2b     = (__hip_bfloat16*)alloc((size_t)NNODES*CLS*2);
  float*          as2     = (float*)alloc((size_t)NNODES*4);
  float*          ad2     = (float*)alloc((size_t)NNODES*4);
  int*            deg     = (int*)alloc((size_t)NNODES*4);
  int*            cursor  = (int*)alloc((size_t)NNODES*4);
  int*            offs    = (int*)alloc((size_t)(NNODES+1)*4);
  int*            bsum    = (int*)alloc((size_t)64*4);
  int*            bbase   = (int*)alloc((size_t)64*4);
  int*            srcsort = (int*)alloc((size_t)E*4);

  (void)hipMemsetAsync(deg, 0, (size_t)NNODES*4, stream);

  // layer 1 projection via MFMA (writes bf16 pairs only)
  wprep_kernel<<<(FIN*D1+255)/256, 256, 0, stream>>>(W1, Wt);
  gemm1_mfma<<<(NNODES+63)/64, 256, 0, stream>>>(x, (const unsigned int*)Wt, h1b);
  alpha1_kernel<<<(NNODES*HH+255)/256, 256, 0, stream>>>(h1b, asrc1, adst1, as1, ad1);

  // CSR by dst (multi-block scan)
  count_kernel<<<(E+255)/256, 256, 0, stream>>>(dsts, deg, E);
  blocksum_kernel<<<NB, 1024, 0, stream>>>(deg, bsum);
  scanbase_kernel<<<1, 64, 0, stream>>>(bsum, bbase);
  scanoffs_kernel<<<NB, 1024, 0, stream>>>(deg, bbase, offs, cursor);
  place_kernel<<<(E+255)/256, 256, 0, stream>>>(srcs, dsts, cursor, srcsort, E);

  // layer 1 attention + aggregation (+bias+ELU)
  agg1_kernel<<<(NNODES+3)/4, 256, 0, stream>>>(h1b, as1, ad1, offs, srcsort, b1, out1);

  // layer 2
  layer2_proj_kernel<<<(NNODES+3)/4, 256, 0, stream>>>(out1, W2, asrc2, adst2, h2b, as2, ad2);
  agg2_kernel<<<(NNODES+3)/4, 256, 0, stream>>>((const unsigned int*)h2b, as2, ad2, offs, srcsort, b2, out);
}

// Round 9
// 162.645 us; speedup vs baseline: 1.4435x; 1.4435x over previous
//
#include <hip/hip_runtime.h>
#include <hip/hip_bf16.h>
#include <math.h>

#define NNODES 50000
#define FIN 256
#define HH 4
#define CC 32
#define D1 128   // H*C
#define CLS 16
#define NBUCK ((NNODES + 255) >> 8)   // 196 buckets of 256 nodes
#define CHUNK 4096

typedef __attribute__((ext_vector_type(8))) short bfrag8;   // 8 bf16 = 4 VGPRs
typedef __attribute__((ext_vector_type(4))) float facc4;

__device__ __forceinline__ float lrelu(float x){ return x > 0.f ? x : 0.2f*x; }

__device__ __forceinline__ unsigned short f2bu(float x){
  __hip_bfloat16 h = __float2bfloat16(x);
  return *reinterpret_cast<unsigned short*>(&h);
}
__device__ __forceinline__ unsigned int pbf(float a, float b){
  return (unsigned int)f2bu(a) | ((unsigned int)f2bu(b) << 16);
}
__device__ __forceinline__ float2 bf2x(unsigned int u){
  float2 r;
  r.x = __uint_as_float(u << 16);
  r.y = __uint_as_float(u & 0xffff0000u);
  return r;
}

// ---------------- W1 prep: Wt[c][k] = bf16(W1[k][c]) ----------------
__global__ void wprep_kernel(const float* __restrict__ W, unsigned short* __restrict__ Wt) {
  int t = blockIdx.x*256 + threadIdx.x;
  if (t >= FIN*D1) return;
  int k = t >> 7, c = t & 127;
  Wt[c*FIN + k] = f2bu(W[t]);
}

// ---------------- GEMM1 via MFMA: h1b = bf16pairs(x @ W1) ----------------
__global__ __launch_bounds__(256) void gemm1_mfma(const float* __restrict__ x,
                                                  const unsigned int* __restrict__ Wt,
                                                  unsigned int* __restrict__ h1b) {
  __shared__ unsigned int Bs[128*256/2];    // 64 KB: Wt swizzled
  __shared__ unsigned int As[64*64/2];      // 8 KB: x tile swizzled
  int tid = threadIdx.x;
  int wv = tid >> 6, lane = tid & 63;
  int r0 = blockIdx.x * 64;

  for (int it = 0; it < 16; it++) {
    int w16 = it*256 + tid;
    int c = w16 >> 5, k8 = w16 & 31;
    uint4 v = ((const uint4*)Wt)[w16];
    int byt = (c*512 + k8*16) ^ ((c&7)<<4);
    *(uint4*)((char*)Bs + byt) = v;
  }

  facc4 acc[8];
  #pragma unroll
  for (int t=0;t<8;t++) acc[t] = (facc4){0.f,0.f,0.f,0.f};

  int arow = tid >> 2, apart = tid & 3;
  int mrow = lane & 15, kb = lane >> 4;

  for (int stage = 0; stage < 4; stage++) {
    int gr = r0 + arow;
    const float* src = x + (size_t)gr*FIN + stage*64 + apart*16;
    float4 f0, f1, f2, f3;
    if (gr < NNODES) {
      f0 = *(const float4*)(src);
      f1 = *(const float4*)(src+4);
      f2 = *(const float4*)(src+8);
      f3 = *(const float4*)(src+12);
    } else {
      f0 = f1 = f2 = f3 = make_float4(0.f,0.f,0.f,0.f);
    }
    uint4 u0, u1;
    u0.x = pbf(f0.x,f0.y); u0.y = pbf(f0.z,f0.w);
    u0.z = pbf(f1.x,f1.y); u0.w = pbf(f1.z,f1.w);
    u1.x = pbf(f2.x,f2.y); u1.y = pbf(f2.z,f2.w);
    u1.z = pbf(f3.x,f3.y); u1.w = pbf(f3.z,f3.w);
    __syncthreads();
    int b0 = (arow*128 + apart*32) ^ ((arow&7)<<4);
    int b1 = (arow*128 + apart*32 + 16) ^ ((arow&7)<<4);
    *(uint4*)((char*)As + b0) = u0;
    *(uint4*)((char*)As + b1) = u1;
    __syncthreads();
    #pragma unroll
    for (int ks = 0; ks < 2; ks++) {
      int row = wv*16 + mrow;
      int abyt = (row*128 + ks*64 + kb*16) ^ ((row&7)<<4);
      bfrag8 afrag = *(bfrag8*)((char*)As + abyt);
      #pragma unroll
      for (int ct = 0; ct < 8; ct++) {
        int c = ct*16 + mrow;
        int bbyt = (c*512 + stage*128 + ks*64 + kb*16) ^ ((c&7)<<4);
        bfrag8 bfrag = *(bfrag8*)((char*)Bs + bbyt);
        acc[ct] = __builtin_amdgcn_mfma_f32_16x16x32_bf16(afrag, bfrag, acc[ct], 0, 0, 0);
      }
    }
  }
  int orow0 = r0 + wv*16 + (lane>>4)*4;
  int ocol = lane & 15;
  #pragma unroll
  for (int r=0; r<4; r++) {
    int gr = orow0 + r;
    if (gr < NNODES) {
      #pragma unroll
      for (int ct=0; ct<4; ct++)
        h1b[(size_t)gr*64 + ct*16 + ocol] = pbf(acc[ct][r], acc[ct+4][r]);
    }
  }
}

// ---------------- per-node alpha for layer 1 (reads bf16 h1b) ----------------
__global__ void alpha1_kernel(const unsigned int* __restrict__ h1b,
                              const float* __restrict__ asrc,
                              const float* __restrict__ adst,
                              float* __restrict__ as1, float* __restrict__ ad1) {
  int t = blockIdx.x * blockDim.x + threadIdx.x;  // i*H + h
  if (t >= NNODES*HH) return;
  int i = t >> 2, h = t & 3;
  const unsigned int* base = h1b + (size_t)i*64 + (h&1)*32;
  const float* ap = asrc + h*CC;
  const float* bp = adst + h*CC;
  bool hi = (h >= 2);
  float s=0.f, d=0.f;
  #pragma unroll
  for (int q8=0; q8<8; q8++){
    uint4 u = *(const uint4*)(base + q8*4);
    float v0 = hi ? bf2x(u.x).y : bf2x(u.x).x;
    float v1 = hi ? bf2x(u.y).y : bf2x(u.y).x;
    float v2 = hi ? bf2x(u.z).y : bf2x(u.z).x;
    float v3 = hi ? bf2x(u.w).y : bf2x(u.w).x;
    int q = q8*4;
    s = fmaf(v0, ap[q+0], s); d = fmaf(v0, bp[q+0], d);
    s = fmaf(v1, ap[q+1], s); d = fmaf(v1, bp[q+1], d);
    s = fmaf(v2, ap[q+2], s); d = fmaf(v2, bp[q+2], d);
    s = fmaf(v3, ap[q+3], s); d = fmaf(v3, bp[q+3], d);
  }
  as1[t] = s; ad1[t] = d;
}

// ================= bucket-binned CSR build (no random 4B scatter) =================
// Phase A: bucket histogram (LDS pre-agg, 196 global adds per block)
__global__ __launch_bounds__(256) void bucket_count_kernel(const int* __restrict__ dsts,
                                                           int* __restrict__ bcnt, int E) {
  __shared__ int cnt[NBUCK];
  for (int t=threadIdx.x; t<NBUCK; t+=256) cnt[t]=0;
  __syncthreads();
  int base = blockIdx.x*CHUNK, lim = min(base+CHUNK, E);
  for (int e = base+threadIdx.x; e < lim; e += 256)
    atomicAdd(&cnt[dsts[e]>>8], 1);
  __syncthreads();
  for (int t=threadIdx.x; t<NBUCK; t+=256)
    if (cnt[t]) atomicAdd(&bcnt[t], cnt[t]);
}

// Phase B: scan bucket sizes -> gstart[NBUCK+1], init gcur
__global__ __launch_bounds__(256) void bucket_scan_kernel(const int* __restrict__ bcnt,
                                                          int* __restrict__ gstart,
                                                          int* __restrict__ gcur) {
  int t = threadIdx.x;
  int orig = (t < NBUCK) ? bcnt[t] : 0;
  int v = orig;
  int ln = t & 63, wv = t >> 6;
  #pragma unroll
  for (int off=1; off<64; off<<=1){ int u=__shfl_up(v,off,64); if(ln>=off) v+=u; }
  __shared__ int wsum[4], wbase[4];
  if (ln==63) wsum[wv]=v;
  __syncthreads();
  if (t==0){
    int s=0;
    for(int k=0;k<4;k++){ wbase[k]=s; s+=wsum[k]; }
  }
  __syncthreads();
  int incl = wbase[wv]+v;
  if (t < NBUCK){ gstart[t+1]=incl; gcur[t]=incl-orig; }
  if (t==0) gstart[0]=0;
}

// Phase C: scatter edges into bucket regions with per-(block,bucket) run reservation.
// packed u32 = src<<8 | (dst&255)  (valid since NNODES < 65536)
__global__ __launch_bounds__(256) void bin_kernel(const int* __restrict__ srcs,
                                                  const int* __restrict__ dsts,
                                                  int* __restrict__ gcur,
                                                  unsigned int* __restrict__ binned, int E) {
  __shared__ int cnt[NBUCK];
  __shared__ int rbase[NBUCK];
  for (int t=threadIdx.x; t<NBUCK; t+=256) cnt[t]=0;
  __syncthreads();
  int base = blockIdx.x*CHUNK, lim = min(base+CHUNK, E);
  for (int e = base+threadIdx.x; e < lim; e += 256)
    atomicAdd(&cnt[dsts[e]>>8], 1);
  __syncthreads();
  for (int t=threadIdx.x; t<NBUCK; t+=256){
    rbase[t] = cnt[t] ? atomicAdd(&gcur[t], cnt[t]) : 0;
    cnt[t] = 0;
  }
  __syncthreads();
  for (int e = base+threadIdx.x; e < lim; e += 256){
    int d = dsts[e], s = srcs[e];
    int b = d >> 8;
    int p = rbase[b] + atomicAdd(&cnt[b], 1);
    binned[p] = ((unsigned int)s << 8) | (unsigned int)(d & 255);
  }
}

// Phase D: one block per bucket -> offs[] + srcsort (u16), all writes contiguous per block
__global__ __launch_bounds__(256) void bucketcsr_kernel(const int* __restrict__ gstart,
                                                        const unsigned int* __restrict__ binned,
                                                        int* __restrict__ offs,
                                                        unsigned short* __restrict__ srcsort, int E) {
  int b = blockIdx.x;
  int s0 = gstart[b], s1 = gstart[b+1];
  int t = threadIdx.x;
  __shared__ int cnt[256];
  __shared__ int cur[256];
  cnt[t] = 0;
  __syncthreads();
  for (int j = s0+t; j < s1; j += 256)
    atomicAdd(&cnt[binned[j] & 255], 1);
  __syncthreads();
  int orig = cnt[t], v = orig;
  int ln = t & 63, wv = t >> 6;
  #pragma unroll
  for (int off=1; off<64; off<<=1){ int u=__shfl_up(v,off,64); if(ln>=off) v+=u; }
  __shared__ int wsum[4], wbase[4];
  if (ln==63) wsum[wv]=v;
  __syncthreads();
  if (t==0){
    int s=0;
    for(int k=0;k<4;k++){ wbase[k]=s; s+=wsum[k]; }
  }
  __syncthreads();
  int excl = wbase[wv] + v - orig;
  cur[t] = excl;
  int node = b*256 + t;
  if (node < NNODES) offs[node] = s0 + excl;
  if (node == NNODES-1) offs[NNODES] = E;
  __syncthreads();
  for (int j = s0+t; j < s1; j += 256){
    unsigned int e = binned[j];
    int p = s0 + atomicAdd(&cur[e & 255], 1);
    srcsort[p] = (unsigned short)(e >> 8);
  }
}

// ---------------- layer-1 softmax + aggregation (+bias+ELU), no-max softmax ----------------
__global__ __launch_bounds__(256) void agg1_kernel(
    const unsigned int* __restrict__ h1b, const float* __restrict__ as1,
    const float* __restrict__ ad1, const int* __restrict__ offs,
    const unsigned short* __restrict__ srcsort, const float* __restrict__ b1,
    float* __restrict__ out1) {
  __shared__ float exs[4][4][64];   // [warp][head][chunk-slot]
  __shared__ int   ss [4][64];
  int warp = threadIdx.x >> 6;
  int lane = threadIdx.x & 63;
  int i = blockIdx.x * 4 + warp;
  if (i >= NNODES) return;
  int start = offs[i], end = offs[i+1];
  float4 adv = *(const float4*)(ad1 + (size_t)i*4);
  float4 asv = *(const float4*)(as1 + (size_t)i*4);
  float ad[4] = {adv.x, adv.y, adv.z, adv.w};
  float wself[4];
  {
    float av[4] = {asv.x, asv.y, asv.z, asv.w};
    #pragma unroll
    for (int h=0;h<4;h++) wself[h] = expf(lrelu(av[h] + ad[h]));
  }
  int hlo = lane >> 5, hhi = hlo + 2;
  float den[4] = {0.f, 0.f, 0.f, 0.f};
  float accA, accB;
  {
    float2 hv = bf2x(h1b[(size_t)i*64 + lane]);
    accA = wself[hlo] * hv.x; accB = wself[hhi] * hv.y;
  }
  for (int c0 = start; c0 < end; c0 += 64) {
    int cnt = min(64, end - c0);
    int j = c0 + lane;
    if (j < end) {
      int s = (int)srcsort[j];
      float4 a = *(const float4*)(as1 + (size_t)s*4);
      float e0 = expf(lrelu(a.x + ad[0]));
      float e1 = expf(lrelu(a.y + ad[1]));
      float e2 = expf(lrelu(a.z + ad[2]));
      float e3 = expf(lrelu(a.w + ad[3]));
      den[0] += e0; den[1] += e1; den[2] += e2; den[3] += e3;
      exs[warp][0][lane] = e0; exs[warp][1][lane] = e1;
      exs[warp][2][lane] = e2; exs[warp][3][lane] = e3;
      ss[warp][lane] = s;
    }
    #pragma unroll 2
    for (int j2 = 0; j2 < cnt; j2++) {
      int s = ss[warp][j2];
      float2 hv = bf2x(h1b[(size_t)s*64 + lane]);
      accA = fmaf(exs[warp][hlo][j2], hv.x, accA);
      accB = fmaf(exs[warp][hhi][j2], hv.y, accB);
    }
  }
  #pragma unroll
  for (int off=1; off<64; off<<=1) {
    #pragma unroll
    for (int h=0;h<4;h++) den[h] += __shfl_xor(den[h], off, 64);
  }
  float invlo = 1.f / (den[hlo] + wself[hlo] + 1e-16f);
  float invhi = 1.f / (den[hhi] + wself[hhi] + 1e-16f);
  float v0 = accA * invlo + b1[lane];
  float v1 = accB * invhi + b1[lane + 64];
  out1[(size_t)i*D1 + lane]      = v0 > 0.f ? v0 : expm1f(v0);
  out1[(size_t)i*D1 + 64 + lane] = v1 > 0.f ? v1 : expm1f(v1);
}

// ---------------- layer-2 projection + alphas (h2 stored bf16) ----------------
__global__ __launch_bounds__(256) void layer2_proj_kernel(
    const float* __restrict__ out1, const float* __restrict__ W2,
    const float* __restrict__ asrc2, const float* __restrict__ adst2,
    __hip_bfloat16* __restrict__ h2b, float* __restrict__ as2, float* __restrict__ ad2) {
  __shared__ float w_s[D1*CLS];
  for (int l = threadIdx.x; l < D1*CLS; l += 256) w_s[l] = W2[l];
  __syncthreads();
  int warp = threadIdx.x >> 6, lane = threadIdx.x & 63;
  int i = blockIdx.x*4 + warp;
  if (i >= NNODES) return;
  int c = lane & 15, kq = lane >> 4;
  float acc = 0.f;
  const float* xp = out1 + (size_t)i*D1 + kq*32;
  #pragma unroll
  for (int q=0; q<8; q++) {
    float4 v = *(const float4*)(xp + q*4);
    int k = kq*32 + q*4;
    acc = fmaf(v.x, w_s[(k+0)*CLS + c], acc);
    acc = fmaf(v.y, w_s[(k+1)*CLS + c], acc);
    acc = fmaf(v.z, w_s[(k+2)*CLS + c], acc);
    acc = fmaf(v.w, w_s[(k+3)*CLS + c], acc);
  }
  acc += __shfl_xor(acc, 16, 64);
  acc += __shfl_xor(acc, 32, 64);
  if (lane < 16) h2b[(size_t)i*CLS + c] = __float2bfloat16(acc);
  float s = acc * asrc2[c];
  float d = acc * adst2[c];
  #pragma unroll
  for (int off=1; off<16; off<<=1) { s += __shfl_xor(s, off, 64); d += __shfl_xor(d, off, 64); }
  if (lane == 0) { as2[i] = s; ad2[i] = d; }
}

// ---------------- layer-2 softmax + aggregation, single pass ----------------
__global__ __launch_bounds__(256) void agg2_kernel(
    const unsigned int* __restrict__ h2b, const float* __restrict__ as2,
    const float* __restrict__ ad2, const int* __restrict__ offs,
    const unsigned short* __restrict__ srcsort, const float* __restrict__ b2,
    float* __restrict__ out) {
  int warp = threadIdx.x >> 6, lane = threadIdx.x & 63;
  int i = blockIdx.x*4 + warp;
  if (i >= NNODES) return;
  int start = offs[i], end = offs[i+1];
  float ad = ad2[i];
  float wself = expf(lrelu(as2[i] + ad));
  int g = lane >> 3, cp = lane & 7;
  float2 acc = make_float2(0.f, 0.f);
  float denp = 0.f;
  if (g == 0) {
    float2 hv = bf2x(h2b[(size_t)i*(CLS/2) + cp]);
    acc.x = wself*hv.x; acc.y = wself*hv.y;
    denp = wself;
  }
  for (int j = start + g; j < end; j += 8) {
    int s = (int)srcsort[j];
    float w = expf(lrelu(as2[s] + ad));
    denp += w;
    float2 hv = bf2x(h2b[(size_t)s*(CLS/2) + cp]);
    acc.x = fmaf(w, hv.x, acc.x);
    acc.y = fmaf(w, hv.y, acc.y);
  }
  #pragma unroll
  for (int off=8; off<64; off<<=1) {
    acc.x += __shfl_xor(acc.x, off, 64);
    acc.y += __shfl_xor(acc.y, off, 64);
    denp  += __shfl_xor(denp,  off, 64);
  }
  if (lane < 8) {
    float inv = 1.f / (denp + 1e-16f);
    float2 o;
    o.x = acc.x * inv + b2[2*cp];
    o.y = acc.y * inv + b2[2*cp+1];
    *(float2*)(out + (size_t)i*CLS + 2*cp) = o;
  }
}

extern "C" void kernel_launch(void* const* d_in, const int* in_sizes, int n_in,
                              void* d_out, int out_size, void* d_ws, size_t ws_size,
                              hipStream_t stream) {
  const float* x     = (const float*)d_in[0];
  const int*   eidx  = (const int*)d_in[1];
  const float* W1    = (const float*)d_in[2];
  const float* asrc1 = (const float*)d_in[3];
  const float* adst1 = (const float*)d_in[4];
  const float* b1    = (const float*)d_in[5];
  const float* W2    = (const float*)d_in[6];
  const float* asrc2 = (const float*)d_in[7];
  const float* adst2 = (const float*)d_in[8];
  const float* b2    = (const float*)d_in[9];
  float* out = (float*)d_out;

  const int E = in_sizes[1] / 2;
  const int* srcs = eidx;
  const int* dsts = eidx + E;
  const int EBLK = (E + CHUNK - 1) / CHUNK;

  char* ws = (char*)d_ws;
  size_t off = 0;
  auto alloc = [&](size_t bytes) -> void* {
    void* p = ws + off;
    off = (off + bytes + 255) & ~(size_t)255;
    return p;
  };
  unsigned int*   h1b     = (unsigned int*)alloc((size_t)NNODES*(D1/2)*4);
  float*          out1    = (float*)alloc((size_t)NNODES*D1*4);
  unsigned short* Wt      = (unsigned short*)alloc((size_t)FIN*D1*2);
  float*          as1     = (float*)alloc((size_t)NNODES*HH*4);
  float*          ad1     = (float*)alloc((size_t)NNODES*HH*4);
  __hip_bfloat16* h2b     = (__hip_bfloat16*)alloc((size_t)NNODES*CLS*2);
  float*          as2     = (float*)alloc((size_t)NNODES*4);
  float*          ad2     = (float*)alloc((size_t)NNODES*4);
  int*            bcnt    = (int*)alloc((size_t)NBUCK*4);
  int*            gstart  = (int*)alloc((size_t)(NBUCK+1)*4);
  int*            gcur    = (int*)alloc((size_t)NBUCK*4);
  int*            offs    = (int*)alloc((size_t)(NNODES+1)*4);
  unsigned int*   binned  = (unsigned int*)alloc((size_t)E*4);
  unsigned short* srcsort = (unsigned short*)alloc((size_t)E*2);

  (void)hipMemsetAsync(bcnt, 0, (size_t)NBUCK*4, stream);

  // layer 1 projection via MFMA (writes bf16 pairs only)
  wprep_kernel<<<(FIN*D1+255)/256, 256, 0, stream>>>(W1, Wt);
  gemm1_mfma<<<(NNODES+63)/64, 256, 0, stream>>>(x, (const unsigned int*)Wt, h1b);
  alpha1_kernel<<<(NNODES*HH+255)/256, 256, 0, stream>>>(h1b, asrc1, adst1, as1, ad1);

  // bucket-binned CSR build
  bucket_count_kernel<<<EBLK, 256, 0, stream>>>(dsts, bcnt, E);
  bucket_scan_kernel<<<1, 256, 0, stream>>>(bcnt, gstart, gcur);
  bin_kernel<<<EBLK, 256, 0, stream>>>(srcs, dsts, gcur, binned, E);
  bucketcsr_kernel<<<NBUCK, 256, 0, stream>>>(gstart, binned, offs, srcsort, E);

  // layer 1 attention + aggregation (+bias+ELU)
  agg1_kernel<<<(NNODES+3)/4, 256, 0, stream>>>(h1b, as1, ad1, offs, srcsort, b1, out1);

  // layer 2
  layer2_proj_kernel<<<(NNODES+3)/4, 256, 0, stream>>>(out1, W2, asrc2, adst2, h2b, as2, ad2);
  agg2_kernel<<<(NNODES+3)/4, 256, 0, stream>>>((const unsigned int*)h2b, as2, ad2, offs, srcsort, b2, out);
}

// Round 10
// 158.516 us; speedup vs baseline: 1.4811x; 1.0260x over previous
//
#include <hip/hip_runtime.h>
#include <hip/hip_bf16.h>
#include <math.h>

#define NNODES 50000
#define FIN 256
#define HH 4
#define CC 32
#define D1 128   // H*C
#define CLS 16
#define NBUCK ((NNODES + 255) >> 8)   // 196 buckets of 256 nodes
#define CHUNK 4096

typedef __attribute__((ext_vector_type(8))) short bfrag8;   // 8 bf16 = 4 VGPRs
typedef __attribute__((ext_vector_type(4))) float facc4;

__device__ __forceinline__ float lrelu(float x){ return x > 0.f ? x : 0.2f*x; }

// fast exp: v_exp_f32 computes 2^x; scores here are bounded (|e| < ~8) so no
// special-case handling needed. 2 inst vs libm expf's ~15.
__device__ __forceinline__ float fexp(float x){
#if __has_builtin(__builtin_amdgcn_exp2f)
  return __builtin_amdgcn_exp2f(x * 1.4426950408889634f);
#else
  return exp2f(x * 1.4426950408889634f);
#endif
}

__device__ __forceinline__ unsigned short f2bu(float x){
  __hip_bfloat16 h = __float2bfloat16(x);
  return *reinterpret_cast<unsigned short*>(&h);
}
__device__ __forceinline__ unsigned int pbf(float a, float b){
  return (unsigned int)f2bu(a) | ((unsigned int)f2bu(b) << 16);
}
__device__ __forceinline__ float2 bf2x(unsigned int u){
  float2 r;
  r.x = __uint_as_float(u << 16);
  r.y = __uint_as_float(u & 0xffff0000u);
  return r;
}

// ---------------- W1 prep: Wt[c][k] = bf16(W1[k][c]) ----------------
__global__ void wprep_kernel(const float* __restrict__ W, unsigned short* __restrict__ Wt) {
  int t = blockIdx.x*256 + threadIdx.x;
  if (t >= FIN*D1) return;
  int k = t >> 7, c = t & 127;
  Wt[c*FIN + k] = f2bu(W[t]);
}

// ---------------- GEMM1 via MFMA: h1b = bf16pairs(x @ W1) ----------------
__global__ __launch_bounds__(256) void gemm1_mfma(const float* __restrict__ x,
                                                  const unsigned int* __restrict__ Wt,
                                                  unsigned int* __restrict__ h1b) {
  __shared__ unsigned int Bs[128*256/2];    // 64 KB: Wt swizzled
  __shared__ unsigned int As[64*64/2];      // 8 KB: x tile swizzled
  int tid = threadIdx.x;
  int wv = tid >> 6, lane = tid & 63;
  int r0 = blockIdx.x * 64;

  for (int it = 0; it < 16; it++) {
    int w16 = it*256 + tid;
    int c = w16 >> 5, k8 = w16 & 31;
    uint4 v = ((const uint4*)Wt)[w16];
    int byt = (c*512 + k8*16) ^ ((c&7)<<4);
    *(uint4*)((char*)Bs + byt) = v;
  }

  facc4 acc[8];
  #pragma unroll
  for (int t=0;t<8;t++) acc[t] = (facc4){0.f,0.f,0.f,0.f};

  int arow = tid >> 2, apart = tid & 3;
  int mrow = lane & 15, kb = lane >> 4;

  for (int stage = 0; stage < 4; stage++) {
    int gr = r0 + arow;
    const float* src = x + (size_t)gr*FIN + stage*64 + apart*16;
    float4 f0, f1, f2, f3;
    if (gr < NNODES) {
      f0 = *(const float4*)(src);
      f1 = *(const float4*)(src+4);
      f2 = *(const float4*)(src+8);
      f3 = *(const float4*)(src+12);
    } else {
      f0 = f1 = f2 = f3 = make_float4(0.f,0.f,0.f,0.f);
    }
    uint4 u0, u1;
    u0.x = pbf(f0.x,f0.y); u0.y = pbf(f0.z,f0.w);
    u0.z = pbf(f1.x,f1.y); u0.w = pbf(f1.z,f1.w);
    u1.x = pbf(f2.x,f2.y); u1.y = pbf(f2.z,f2.w);
    u1.z = pbf(f3.x,f3.y); u1.w = pbf(f3.z,f3.w);
    __syncthreads();
    int b0 = (arow*128 + apart*32) ^ ((arow&7)<<4);
    int b1 = (arow*128 + apart*32 + 16) ^ ((arow&7)<<4);
    *(uint4*)((char*)As + b0) = u0;
    *(uint4*)((char*)As + b1) = u1;
    __syncthreads();
    #pragma unroll
    for (int ks = 0; ks < 2; ks++) {
      int row = wv*16 + mrow;
      int abyt = (row*128 + ks*64 + kb*16) ^ ((row&7)<<4);
      bfrag8 afrag = *(bfrag8*)((char*)As + abyt);
      #pragma unroll
      for (int ct = 0; ct < 8; ct++) {
        int c = ct*16 + mrow;
        int bbyt = (c*512 + stage*128 + ks*64 + kb*16) ^ ((c&7)<<4);
        bfrag8 bfrag = *(bfrag8*)((char*)Bs + bbyt);
        acc[ct] = __builtin_amdgcn_mfma_f32_16x16x32_bf16(afrag, bfrag, acc[ct], 0, 0, 0);
      }
    }
  }
  int orow0 = r0 + wv*16 + (lane>>4)*4;
  int ocol = lane & 15;
  #pragma unroll
  for (int r=0; r<4; r++) {
    int gr = orow0 + r;
    if (gr < NNODES) {
      #pragma unroll
      for (int ct=0; ct<4; ct++)
        h1b[(size_t)gr*64 + ct*16 + ocol] = pbf(acc[ct][r], acc[ct+4][r]);
    }
  }
}

// ---------------- per-node alpha for layer 1 (reads bf16 h1b) ----------------
__global__ void alpha1_kernel(const unsigned int* __restrict__ h1b,
                              const float* __restrict__ asrc,
                              const float* __restrict__ adst,
                              float* __restrict__ as1, float* __restrict__ ad1) {
  int t = blockIdx.x * blockDim.x + threadIdx.x;  // i*H + h
  if (t >= NNODES*HH) return;
  int i = t >> 2, h = t & 3;
  const unsigned int* base = h1b + (size_t)i*64 + (h&1)*32;
  const float* ap = asrc + h*CC;
  const float* bp = adst + h*CC;
  bool hi = (h >= 2);
  float s=0.f, d=0.f;
  #pragma unroll
  for (int q8=0; q8<8; q8++){
    uint4 u = *(const uint4*)(base + q8*4);
    float v0 = hi ? bf2x(u.x).y : bf2x(u.x).x;
    float v1 = hi ? bf2x(u.y).y : bf2x(u.y).x;
    float v2 = hi ? bf2x(u.z).y : bf2x(u.z).x;
    float v3 = hi ? bf2x(u.w).y : bf2x(u.w).x;
    int q = q8*4;
    s = fmaf(v0, ap[q+0], s); d = fmaf(v0, bp[q+0], d);
    s = fmaf(v1, ap[q+1], s); d = fmaf(v1, bp[q+1], d);
    s = fmaf(v2, ap[q+2], s); d = fmaf(v2, bp[q+2], d);
    s = fmaf(v3, ap[q+3], s); d = fmaf(v3, bp[q+3], d);
  }
  as1[t] = s; ad1[t] = d;
}

// ================= bucket-binned CSR build (no random 4B scatter) =================
__global__ __launch_bounds__(256) void bucket_count_kernel(const int* __restrict__ dsts,
                                                           int* __restrict__ bcnt, int E) {
  __shared__ int cnt[NBUCK];
  for (int t=threadIdx.x; t<NBUCK; t+=256) cnt[t]=0;
  __syncthreads();
  int base = blockIdx.x*CHUNK, lim = min(base+CHUNK, E);
  for (int e = base+threadIdx.x; e < lim; e += 256)
    atomicAdd(&cnt[dsts[e]>>8], 1);
  __syncthreads();
  for (int t=threadIdx.x; t<NBUCK; t+=256)
    if (cnt[t]) atomicAdd(&bcnt[t], cnt[t]);
}

__global__ __launch_bounds__(256) void bucket_scan_kernel(const int* __restrict__ bcnt,
                                                          int* __restrict__ gstart,
                                                          int* __restrict__ gcur) {
  int t = threadIdx.x;
  int orig = (t < NBUCK) ? bcnt[t] : 0;
  int v = orig;
  int ln = t & 63, wv = t >> 6;
  #pragma unroll
  for (int off=1; off<64; off<<=1){ int u=__shfl_up(v,off,64); if(ln>=off) v+=u; }
  __shared__ int wsum[4], wbase[4];
  if (ln==63) wsum[wv]=v;
  __syncthreads();
  if (t==0){
    int s=0;
    for(int k=0;k<4;k++){ wbase[k]=s; s+=wsum[k]; }
  }
  __syncthreads();
  int incl = wbase[wv]+v;
  if (t < NBUCK){ gstart[t+1]=incl; gcur[t]=incl-orig; }
  if (t==0) gstart[0]=0;
}

__global__ __launch_bounds__(256) void bin_kernel(const int* __restrict__ srcs,
                                                  const int* __restrict__ dsts,
                                                  int* __restrict__ gcur,
                                                  unsigned int* __restrict__ binned, int E) {
  __shared__ int cnt[NBUCK];
  __shared__ int rbase[NBUCK];
  for (int t=threadIdx.x; t<NBUCK; t+=256) cnt[t]=0;
  __syncthreads();
  int base = blockIdx.x*CHUNK, lim = min(base+CHUNK, E);
  for (int e = base+threadIdx.x; e < lim; e += 256)
    atomicAdd(&cnt[dsts[e]>>8], 1);
  __syncthreads();
  for (int t=threadIdx.x; t<NBUCK; t+=256){
    rbase[t] = cnt[t] ? atomicAdd(&gcur[t], cnt[t]) : 0;
    cnt[t] = 0;
  }
  __syncthreads();
  for (int e = base+threadIdx.x; e < lim; e += 256){
    int d = dsts[e], s = srcs[e];
    int b = d >> 8;
    int p = rbase[b] + atomicAdd(&cnt[b], 1);
    binned[p] = ((unsigned int)s << 8) | (unsigned int)(d & 255);
  }
}

__global__ __launch_bounds__(256) void bucketcsr_kernel(const int* __restrict__ gstart,
                                                        const unsigned int* __restrict__ binned,
                                                        int* __restrict__ offs,
                                                        unsigned short* __restrict__ srcsort, int E) {
  int b = blockIdx.x;
  int s0 = gstart[b], s1 = gstart[b+1];
  int t = threadIdx.x;
  __shared__ int cnt[256];
  __shared__ int cur[256];
  cnt[t] = 0;
  __syncthreads();
  for (int j = s0+t; j < s1; j += 256)
    atomicAdd(&cnt[binned[j] & 255], 1);
  __syncthreads();
  int orig = cnt[t], v = orig;
  int ln = t & 63, wv = t >> 6;
  #pragma unroll
  for (int off=1; off<64; off<<=1){ int u=__shfl_up(v,off,64); if(ln>=off) v+=u; }
  __shared__ int wsum[4], wbase[4];
  if (ln==63) wsum[wv]=v;
  __syncthreads();
  if (t==0){
    int s=0;
    for(int k=0;k<4;k++){ wbase[k]=s; s+=wsum[k]; }
  }
  __syncthreads();
  int excl = wbase[wv] + v - orig;
  cur[t] = excl;
  int node = b*256 + t;
  if (node < NNODES) offs[node] = s0 + excl;
  if (node == NNODES-1) offs[NNODES] = E;
  __syncthreads();
  for (int j = s0+t; j < s1; j += 256){
    unsigned int e = binned[j];
    int p = s0 + atomicAdd(&cur[e & 255], 1);
    srcsort[p] = (unsigned short)(e >> 8);
  }
}

// ---------------- layer-1 softmax + aggregation (+bias+ELU), no-max softmax ----------------
// out1p pair word p = bf16(channel p, channel p+64)
__global__ __launch_bounds__(256) void agg1_kernel(
    const unsigned int* __restrict__ h1b, const float* __restrict__ as1,
    const float* __restrict__ ad1, const int* __restrict__ offs,
    const unsigned short* __restrict__ srcsort, const float* __restrict__ b1,
    unsigned int* __restrict__ out1p) {
  __shared__ float exs[4][4][64];   // [warp][head][chunk-slot]
  __shared__ int   ss [4][64];
  int warp = threadIdx.x >> 6;
  int lane = threadIdx.x & 63;
  int i = blockIdx.x * 4 + warp;
  if (i >= NNODES) return;
  int start = offs[i], end = offs[i+1];
  float4 adv = *(const float4*)(ad1 + (size_t)i*4);
  float4 asv = *(const float4*)(as1 + (size_t)i*4);
  float ad[4] = {adv.x, adv.y, adv.z, adv.w};
  float wself[4];
  {
    float av[4] = {asv.x, asv.y, asv.z, asv.w};
    #pragma unroll
    for (int h=0;h<4;h++) wself[h] = fexp(lrelu(av[h] + ad[h]));
  }
  int hlo = lane >> 5, hhi = hlo + 2;
  float den[4] = {0.f, 0.f, 0.f, 0.f};
  float accA, accB;
  {
    float2 hv = bf2x(h1b[(size_t)i*64 + lane]);
    accA = wself[hlo] * hv.x; accB = wself[hhi] * hv.y;
  }
  for (int c0 = start; c0 < end; c0 += 64) {
    int cnt = min(64, end - c0);
    int j = c0 + lane;
    if (j < end) {
      int s = (int)srcsort[j];
      float4 a = *(const float4*)(as1 + (size_t)s*4);
      float e0 = fexp(lrelu(a.x + ad[0]));
      float e1 = fexp(lrelu(a.y + ad[1]));
      float e2 = fexp(lrelu(a.z + ad[2]));
      float e3 = fexp(lrelu(a.w + ad[3]));
      den[0] += e0; den[1] += e1; den[2] += e2; den[3] += e3;
      exs[warp][0][lane] = e0; exs[warp][1][lane] = e1;
      exs[warp][2][lane] = e2; exs[warp][3][lane] = e3;
      ss[warp][lane] = s;
    }
    // 8 loads in flight: the gathers are independent (addresses known after
    // fill) — deep unroll hides the ~500cy L2/L3-miss latency (round-9 finding).
    #pragma unroll 8
    for (int j2 = 0; j2 < cnt; j2++) {
      int s = ss[warp][j2];
      float2 hv = bf2x(h1b[(size_t)s*64 + lane]);
      accA = fmaf(exs[warp][hlo][j2], hv.x, accA);
      accB = fmaf(exs[warp][hhi][j2], hv.y, accB);
    }
  }
  #pragma unroll
  for (int off=1; off<64; off<<=1) {
    #pragma unroll
    for (int h=0;h<4;h++) den[h] += __shfl_xor(den[h], off, 64);
  }
  float invlo = 1.f / (den[hlo] + wself[hlo] + 1e-16f);
  float invhi = 1.f / (den[hhi] + wself[hhi] + 1e-16f);
  float v0 = accA * invlo + b1[lane];
  float v1 = accB * invhi + b1[lane + 64];
  v0 = v0 > 0.f ? v0 : fexp(v0) - 1.f;   // ELU
  v1 = v1 > 0.f ? v1 : fexp(v1) - 1.f;
  out1p[(size_t)i*64 + lane] = pbf(v0, v1);
}

// ---------------- layer-2 projection + alphas (reads bf16-pair out1) ----------------
__global__ __launch_bounds__(256) void layer2_proj_kernel(
    const unsigned int* __restrict__ out1p, const float* __restrict__ W2,
    const float* __restrict__ asrc2, const float* __restrict__ adst2,
    __hip_bfloat16* __restrict__ h2b, float* __restrict__ as2, float* __restrict__ ad2) {
  __shared__ float w_s[D1*CLS];
  for (int l = threadIdx.x; l < D1*CLS; l += 256) w_s[l] = W2[l];
  __syncthreads();
  int warp = threadIdx.x >> 6, lane = threadIdx.x & 63;
  int i = blockIdx.x*4 + warp;
  if (i >= NNODES) return;
  int c = lane & 15, kq = lane >> 4;
  // kq 0: words 0..31 lo (k=0..31); kq 1: words 32..63 lo (k=32..63);
  // kq 2: words 0..31 hi (k=64..95); kq 3: words 32..63 hi (k=96..127)
  const unsigned int* xp = out1p + (size_t)i*64 + (kq&1)*32;
  bool hi = kq >= 2;
  int kb = (kq&1)*32 + (hi ? 64 : 0);
  float acc = 0.f;
  #pragma unroll
  for (int q8=0; q8<8; q8++) {
    uint4 u = *(const uint4*)(xp + q8*4);
    float v0 = hi ? bf2x(u.x).y : bf2x(u.x).x;
    float v1 = hi ? bf2x(u.y).y : bf2x(u.y).x;
    float v2 = hi ? bf2x(u.z).y : bf2x(u.z).x;
    float v3 = hi ? bf2x(u.w).y : bf2x(u.w).x;
    int k = kb + q8*4;
    acc = fmaf(v0, w_s[(k+0)*CLS + c], acc);
    acc = fmaf(v1, w_s[(k+1)*CLS + c], acc);
    acc = fmaf(v2, w_s[(k+2)*CLS + c], acc);
    acc = fmaf(v3, w_s[(k+3)*CLS + c], acc);
  }
  acc += __shfl_xor(acc, 16, 64);
  acc += __shfl_xor(acc, 32, 64);
  if (lane < 16) h2b[(size_t)i*CLS + c] = __float2bfloat16(acc);
  float s = acc * asrc2[c];
  float d = acc * adst2[c];
  #pragma unroll
  for (int off=1; off<16; off<<=1) { s += __shfl_xor(s, off, 64); d += __shfl_xor(d, off, 64); }
  if (lane == 0) { as2[i] = s; ad2[i] = d; }
}

// ---------------- layer-2 softmax + aggregation, single pass ----------------
__global__ __launch_bounds__(256) void agg2_kernel(
    const unsigned int* __restrict__ h2b, const float* __restrict__ as2,
    const float* __restrict__ ad2, const int* __restrict__ offs,
    const unsigned short* __restrict__ srcsort, const float* __restrict__ b2,
    float* __restrict__ out) {
  int warp = threadIdx.x >> 6, lane = threadIdx.x & 63;
  int i = blockIdx.x*4 + warp;
  if (i >= NNODES) return;
  int start = offs[i], end = offs[i+1];
  float ad = ad2[i];
  float wself = fexp(lrelu(as2[i] + ad));
  int g = lane >> 3, cp = lane & 7;
  float2 acc = make_float2(0.f, 0.f);
  float denp = 0.f;
  if (g == 0) {
    float2 hv = bf2x(h2b[(size_t)i*(CLS/2) + cp]);
    acc.x = wself*hv.x; acc.y = wself*hv.y;
    denp = wself;
  }
  #pragma unroll 4
  for (int j = start + g; j < end; j += 8) {
    int s = (int)srcsort[j];
    float w = fexp(lrelu(as2[s] + ad));
    denp += w;
    float2 hv = bf2x(h2b[(size_t)s*(CLS/2) + cp]);
    acc.x = fmaf(w, hv.x, acc.x);
    acc.y = fmaf(w, hv.y, acc.y);
  }
  #pragma unroll
  for (int off=8; off<64; off<<=1) {
    acc.x += __shfl_xor(acc.x, off, 64);
    acc.y += __shfl_xor(acc.y, off, 64);
    denp  += __shfl_xor(denp,  off, 64);
  }
  if (lane < 8) {
    float inv = 1.f / (denp + 1e-16f);
    float2 o;
    o.x = acc.x * inv + b2[2*cp];
    o.y = acc.y * inv + b2[2*cp+1];
    *(float2*)(out + (size_t)i*CLS + 2*cp) = o;
  }
}

extern "C" void kernel_launch(void* const* d_in, const int* in_sizes, int n_in,
                              void* d_out, int out_size, void* d_ws, size_t ws_size,
                              hipStream_t stream) {
  const float* x     = (const float*)d_in[0];
  const int*   eidx  = (const int*)d_in[1];
  const float* W1    = (const float*)d_in[2];
  const float* asrc1 = (const float*)d_in[3];
  const float* adst1 = (const float*)d_in[4];
  const float* b1    = (const float*)d_in[5];
  const float* W2    = (const float*)d_in[6];
  const float* asrc2 = (const float*)d_in[7];
  const float* adst2 = (const float*)d_in[8];
  const float* b2    = (const float*)d_in[9];
  float* out = (float*)d_out;

  const int E = in_sizes[1] / 2;
  const int* srcs = eidx;
  const int* dsts = eidx + E;
  const int EBLK = (E + CHUNK - 1) / CHUNK;

  char* ws = (char*)d_ws;
  size_t off = 0;
  auto alloc = [&](size_t bytes) -> void* {
    void* p = ws + off;
    off = (off + bytes + 255) & ~(size_t)255;
    return p;
  };
  unsigned int*   h1b     = (unsigned int*)alloc((size_t)NNODES*(D1/2)*4);
  unsigned int*   out1p   = (unsigned int*)alloc((size_t)NNODES*(D1/2)*4);
  unsigned short* Wt      = (unsigned short*)alloc((size_t)FIN*D1*2);
  float*          as1     = (float*)alloc((size_t)NNODES*HH*4);
  float*          ad1     = (float*)alloc((size_t)NNODES*HH*4);
  __hip_bfloat16* h2b     = (__hip_bfloat16*)alloc((size_t)NNODES*CLS*2);
  float*          as2     = (float*)alloc((size_t)NNODES*4);
  float*          ad2     = (float*)alloc((size_t)NNODES*4);
  int*            bcnt    = (int*)alloc((size_t)NBUCK*4);
  int*            gstart  = (int*)alloc((size_t)(NBUCK+1)*4);
  int*            gcur    = (int*)alloc((size_t)NBUCK*4);
  int*            offs    = (int*)alloc((size_t)(NNODES+1)*4);
  unsigned int*   binned  = (unsigned int*)alloc((size_t)E*4);
  unsigned short* srcsort = (unsigned short*)alloc((size_t)E*2);

  (void)hipMemsetAsync(bcnt, 0, (size_t)NBUCK*4, stream);

  // layer 1 projection via MFMA (writes bf16 pairs only)
  wprep_kernel<<<(FIN*D1+255)/256, 256, 0, stream>>>(W1, Wt);
  gemm1_mfma<<<(NNODES+63)/64, 256, 0, stream>>>(x, (const unsigned int*)Wt, h1b);
  alpha1_kernel<<<(NNODES*HH+255)/256, 256, 0, stream>>>(h1b, asrc1, adst1, as1, ad1);

  // bucket-binned CSR build
  bucket_count_kernel<<<EBLK, 256, 0, stream>>>(dsts, bcnt, E);
  bucket_scan_kernel<<<1, 256, 0, stream>>>(bcnt, gstart, gcur);
  bin_kernel<<<EBLK, 256, 0, stream>>>(srcs, dsts, gcur, binned, E);
  bucketcsr_kernel<<<NBUCK, 256, 0, stream>>>(gstart, binned, offs, srcsort, E);

  // layer 1 attention + aggregation (+bias+ELU)
  agg1_kernel<<<(NNODES+3)/4, 256, 0, stream>>>(h1b, as1, ad1, offs, srcsort, b1, out1p);

  // layer 2
  layer2_proj_kernel<<<(NNODES+3)/4, 256, 0, stream>>>(out1p, W2, asrc2, adst2, h2b, as2, ad2);
  agg2_kernel<<<(NNODES+3)/4, 256, 0, stream>>>((const unsigned int*)h2b, as2, ad2, offs, srcsort, b2, out);
}